// Round 8
// baseline (1563.762 us; speedup 1.0000x reference)
//
#include <hip/hip_runtime.h>
#include <hip/hip_bf16.h>
#include <hip/hip_fp16.h>

// Problem: B=64, T=1024, INPUT=256, HIDDEN=512, OUTPUT=256
//   xh = x @ W_xh + b_h
//   h_t = tanh(h_{t-1} @ W_hh + xh_t)   (serial over t)
//   out = hs @ W_hy + b_y
//
// Round 10 = round 9 + forced W register residency.
// Round-9 post-mortem: VGPR_Count=52 (W[16]=64 regs not resident) and the
// implied W stream = 31.4 TB/s = 91% of L2 peak -> the scan is L2-BW-bound on
// a stream that shouldn't exist. Remat of loads from __restrict__ const
// memory is always LEGAL, so clobbers/attributes can't stop it; instead each
// W word is passed through an inline-asm identity ("+v") -> the values are
// asm-defined, remat is impossible, and 64 words stay in VGPRs (~130 live
// regs < the 256 budget of __launch_bounds__(512,2), so no spill).

#define BT 65536      // B*T
#define HID 512
#define NIN 256
#define NOUT 256
#define TSTEPS 1024
#define NBATCH 64

typedef _Float16 hf2_t __attribute__((ext_vector_type(2)));

__device__ __forceinline__ float fdot2(unsigned w, unsigned h, float acc) {
#if __has_builtin(__builtin_amdgcn_fdot2)
    return __builtin_amdgcn_fdot2(__builtin_bit_cast(hf2_t, w),
                                  __builtin_bit_cast(hf2_t, h), acc, false);
#else
    __half2 wv = __builtin_bit_cast(__half2, w);
    __half2 hv = __builtin_bit_cast(__half2, h);
    float2 wf = __half22float2(wv);
    float2 hf = __half22float2(hv);
    return acc + wf.x * hf.x + wf.y * hf.y;
#endif
}

__device__ __forceinline__ float dot4(uint4 w, uint4 h, float acc) {
    acc = fdot2(w.x, h.x, acc);
    acc = fdot2(w.y, h.y, acc);
    acc = fdot2(w.z, h.z, acc);
    acc = fdot2(w.w, h.w, acc);
    return acc;
}

__device__ __forceinline__ unsigned pack2h(float a, float b) {
    unsigned lo = (unsigned)__half_as_ushort(__float2half_rn(a));
    unsigned hi = (unsigned)__half_as_ushort(__float2half_rn(b));
    return lo | (hi << 16);
}

// cross-lane add via DPP (VALU pipe, no LDS).
// 0xB1 = quad_perm xor1, 0x4E = quad_perm xor2, 0x141 = row_half_mirror
// (after xor1+xor2, swaps the two quad-sums of each 8-lane group -> 8-reduce).
template <int CTRL>
__device__ __forceinline__ float dpp_add(float x) {
    int y = __builtin_amdgcn_mov_dpp(__float_as_int(x), CTRL, 0xF, 0xF, true);
    return x + __int_as_float(y);
}
template <int CTRL>
__device__ __forceinline__ float dpp_get(float x) {
    int y = __builtin_amdgcn_mov_dpp(__float_as_int(x), CTRL, 0xF, 0xF, true);
    return __int_as_float(y);
}

// tanh(x) = 1 - 2/(e^{2x}+1); e^{2x} via v_exp_f32, division via v_rcp_f32.
__device__ __forceinline__ float fast_tanh(float x) {
    float e = __builtin_amdgcn_exp2f(x * 2.8853900817779268f);   // 2*log2(e)
    return 1.0f - 2.0f * __builtin_amdgcn_rcpf(e + 1.0f);
}

// ---------- generic load/store helpers ----------
__device__ __forceinline__ float4 load4f(const float* p) {
    return *(const float4*)p;
}
__device__ __forceinline__ float4 load4f(const __half* p) {
    ushort4 u = *(const ushort4*)p;
    float4 r;
    r.x = __half2float(__ushort_as_half(u.x));
    r.y = __half2float(__ushort_as_half(u.y));
    r.z = __half2float(__ushort_as_half(u.z));
    r.w = __half2float(__ushort_as_half(u.w));
    return r;
}
__device__ __forceinline__ void store1(float* p, float v) { *p = v; }
__device__ __forceinline__ void store1(__half* p, float v) { *p = __float2half_rn(v); }

// ---------- pack W_hh (f32 [k][col]) into per-thread f16 blobs ----------
// Scan WG quarter q, thread t (g=t>>3, s=t&7): cols {128q+2g, 128q+2g+1},
// k in [64s, 64s+64). W uint4 i = c*8+j (c=0..1, j=0..7), word u:
// pack(W[64s+8j+2u][128q+2g+c], W[64s+8j+2u+1][...]).
// Layout wblob[(q*16+i)*512 + t] (uint4), coalesced on t.
// Also zeroes the 32768-u64 exchange buffer (per-launch tag reset).
__global__ __launch_bounds__(256)
void pack_w4_kernel(const float* __restrict__ W,
                    unsigned* __restrict__ wblob_w,
                    unsigned long long* __restrict__ exch) {
    int w = blockIdx.x * 256 + threadIdx.x;   // 0..131071
    int q = w >> 15;
    int r = w & 32767;
    int i = r >> 11;
    int r2 = r & 2047;
    int t = r2 >> 2, u = r2 & 3;
    int g = t >> 3, s = t & 7;
    int c = i >> 3, j = i & 7;
    int col = 128 * q + 2 * g + c;
    int k = 64 * s + 8 * j + 2 * u;
    unsigned val = pack2h(W[(size_t)k * HID + col], W[(size_t)(k + 1) * HID + col]);
    wblob_w[(size_t)((q * 16 + i) * 512 + t) * 4 + u] = val;
    if (w < 32768) exch[w] = 0ull;            // graph-replay-safe tag reset
}

// ---------- f32 tiled GEMM with bias: C[M,N] = A[M,K] @ B[K,N] + bias[N] ----------
// Used only for xh = x @ W_xh + b_h (precision feeds the recurrence).
template <typename AT, typename CT>
__global__ __launch_bounds__(256)
void gemm_bias_kernel(const AT* __restrict__ A, const float* __restrict__ B,
                      const float* __restrict__ bias, CT* __restrict__ C,
                      int M, int N, int K) {
    const int TM = 64, TN = 64, TK = 16;
    __shared__ float As[TK][TM];
    __shared__ float Bs[TK][TN + 4];

    int tid = threadIdx.x;
    int tx = tid & 15;
    int ty = tid >> 4;
    int row0 = blockIdx.x * TM;
    int col0 = blockIdx.y * TN;

    float c[4][4];
#pragma unroll
    for (int i = 0; i < 4; ++i)
#pragma unroll
        for (int j = 0; j < 4; ++j) c[i][j] = 0.f;

    for (int kk = 0; kk < K; kk += TK) {
        {
            int ar = tid >> 2;
            int ac = (tid & 3) * 4;
            float4 av = load4f(A + (size_t)(row0 + ar) * K + kk + ac);
            As[ac + 0][ar] = av.x;
            As[ac + 1][ar] = av.y;
            As[ac + 2][ar] = av.z;
            As[ac + 3][ar] = av.w;
        }
        {
            int br = tid >> 4;
            int bc = (tid & 15) * 4;
            float4 bv = *(const float4*)(B + (size_t)(kk + br) * N + col0 + bc);
            *(float4*)&Bs[br][bc] = bv;
        }
        __syncthreads();
#pragma unroll
        for (int k = 0; k < TK; ++k) {
            float4 a = *(const float4*)&As[k][ty * 4];
            float4 b = *(const float4*)&Bs[k][tx * 4];
            float av[4] = {a.x, a.y, a.z, a.w};
            float bv[4] = {b.x, b.y, b.z, b.w};
#pragma unroll
            for (int i = 0; i < 4; ++i)
#pragma unroll
                for (int j = 0; j < 4; ++j) c[i][j] += av[i] * bv[j];
        }
        __syncthreads();
    }

#pragma unroll
    for (int j = 0; j < 4; ++j) {
        float bb = bias[col0 + tx * 4 + j];
#pragma unroll
        for (int i = 0; i < 4; ++i) {
            int r = row0 + ty * 4 + i;
            int cc = col0 + tx * 4 + j;
            store1(&C[(size_t)r * N + cc], c[i][j] + bb);
        }
    }
}

// ---------- packed-f16 dot2 GEMM with bias (2 MACs/instr) ----------
// Used for out = hs @ W_hy + b_y: A is already f16; error does not recurse.
template <typename AT, typename CT>
__global__ __launch_bounds__(256)
void gemm_bias_f16_kernel(const AT* __restrict__ A, const float* __restrict__ B,
                          const float* __restrict__ bias, CT* __restrict__ C,
                          int M, int N, int K) {
    const int TM = 64, TN = 64, TK = 16;
    __shared__ unsigned Asp[TK / 2][TM];
    __shared__ unsigned Bsp[TK / 2][TN + 4];

    int tid = threadIdx.x;
    int tx = tid & 15;
    int ty = tid >> 4;
    int row0 = blockIdx.x * TM;
    int col0 = blockIdx.y * TN;

    float c[4][4];
#pragma unroll
    for (int i = 0; i < 4; ++i)
#pragma unroll
        for (int j = 0; j < 4; ++j) c[i][j] = 0.f;

    for (int kk = 0; kk < K; kk += TK) {
        {
            int ar = tid >> 2;
            int ac = (tid & 3) * 4;
            float4 av = load4f(A + (size_t)(row0 + ar) * K + kk + ac);
            Asp[(ac >> 1) + 0][ar] = pack2h(av.x, av.y);
            Asp[(ac >> 1) + 1][ar] = pack2h(av.z, av.w);
        }
        {
            int k2 = tid >> 5;
            int bc = (tid & 31) * 2;
            const float* b0 = B + (size_t)(kk + 2 * k2) * N + col0 + bc;
            const float* b1 = b0 + N;
            float2 r0 = *(const float2*)b0;
            float2 r1 = *(const float2*)b1;
            Bsp[k2][bc + 0] = pack2h(r0.x, r1.x);
            Bsp[k2][bc + 1] = pack2h(r0.y, r1.y);
        }
        __syncthreads();
#pragma unroll
        for (int k2 = 0; k2 < TK / 2; ++k2) {
            uint4 ap = *(const uint4*)&Asp[k2][ty * 4];
            uint4 bp = *(const uint4*)&Bsp[k2][tx * 4];
            unsigned av[4] = {ap.x, ap.y, ap.z, ap.w};
            unsigned bv[4] = {bp.x, bp.y, bp.z, bp.w};
#pragma unroll
            for (int i = 0; i < 4; ++i)
#pragma unroll
                for (int j = 0; j < 4; ++j) c[i][j] = fdot2(av[i], bv[j], c[i][j]);
        }
        __syncthreads();
    }

#pragma unroll
    for (int j = 0; j < 4; ++j) {
        float bb = bias[col0 + tx * 4 + j];
#pragma unroll
        for (int i = 0; i < 4; ++i) {
            int r = row0 + ty * 4 + i;
            int cc = col0 + tx * 4 + j;
            store1(&C[(size_t)r * N + cc], c[i][j] + bb);
        }
    }
}

// ---------- scan: 4 WGs per batch row (column quarters), all-reg W ----------
// h2-index H (0..255) lives at LDS word (H>>5)*36 + (H&31)  (uint4-slot
// stride 9 per 8: slice s's 8 uint4 start at slot s*9 -> the 8 per-wave
// broadcast reads hit disjoint bank quads).
// exch word: [row][parity][quarter][g] u64 = (tag<<32) | packed 2xf16.
// tag = step+1, parity = (step+1)&1; consumer at step t polls tag >= t.
__global__ __launch_bounds__(512, 2)
void rnn_scan4(const __half* __restrict__ xh,
               const uint4* __restrict__ wblob,            // [4][16][512]
               __half* __restrict__ hs,
               unsigned long long* __restrict__ exch) {    // [64][2][4][64]
    __shared__ __align__(16) uint4 hbuf4[2][72];           // 2304 B, h double-buffer

    const int bid = blockIdx.x;          // 0..255
    const int row = bid & 63;            // batch row; group shares bid%8 (XCD)
    const int q   = bid >> 6;            // column quarter: cols [128q,128q+128)
    const int t = threadIdx.x;
    const int g = t >> 3, s = t & 7;     // col pair group / k-slice [64s,64s+64)

    // whole weight slice: 16 uint4 = 64 VGPRs
    uint4 W[16];
#pragma unroll
    for (int i = 0; i < 16; ++i) W[i] = wblob[(q * 16 + i) * 512 + t];
    // Force residency: each word becomes the RESULT OF AN ASM OP. LLVM cannot
    // rematerialize inline asm, so re-loading from wblob inside the loop is
    // no longer a legal substitute -> the 64 words stay in VGPRs.
    // (rocprof VGPR_Count ~52 -> ~130 is the verification bit.)
#pragma unroll
    for (int i = 0; i < 16; ++i) {
        asm volatile("" : "+v"(W[i].x), "+v"(W[i].y), "+v"(W[i].z), "+v"(W[i].w));
    }

    if (t < 72) {
        hbuf4[0][t] = uint4{0u, 0u, 0u, 0u};
        hbuf4[1][t] = uint4{0u, 0u, 0u, 0u};
    }
    __syncthreads();

    const int col0 = 128 * q + 2 * g;    // lane s<2 finalizes col0+s
    const __half* xp = xh + (size_t)row * TSTEPS * HID + col0 + s;
    // hs output as u32 (h2 pair): base word = row*T*256 + (64q+g), +256/step
    unsigned* hp32 = (unsigned*)hs + (size_t)row * TSTEPS * 256 + (64 * q + g);
    // own-quarter LDS write slot: H = 64q+g
    const int wordC = ((64 * q + g) >> 5) * 36 + ((64 * q + g) & 31);
    // publish pointers (per parity)
    unsigned long long* pub[2];
    pub[0] = exch + (((size_t)row * 2 + 0) * 4 + q) * 64 + g;
    pub[1] = exch + (((size_t)row * 2 + 1) * 4 + q) * 64 + g;
    // loader role: threads 0..191 fetch the 3 partner quarters (64 u64 each)
    const int m = t & 63;
    const int qa = t >> 6;                           // 0..2 for loaders
    const int Q = qa + (qa >= q ? 1 : 0);            // absolute partner quarter
    const unsigned long long* src[2];
    src[0] = exch + (((size_t)row * 2 + 0) * 4 + Q) * 64 + m;
    src[1] = exch + (((size_t)row * 2 + 1) * 4 + Q) * 64 + m;
    const int ldsw = ((64 * Q + m) >> 5) * 36 + ((64 * Q + m) & 31);

    for (int step = 0; step < TSTEPS; ++step) {
        const int par = step & 1;

        float xv = 0.f;
        if (s < 2) xv = __half2float(xp[(size_t)step * HID]);   // early issue

        if (step && t < 192) {
            // poll: a successful read carries the data (tag+payload in one u64)
            unsigned long long v = __hip_atomic_load(
                src[par], __ATOMIC_RELAXED, __HIP_MEMORY_SCOPE_AGENT);
            while ((unsigned)(v >> 32) < (unsigned)step) {
                v = __hip_atomic_load(src[par], __ATOMIC_RELAXED,
                                      __HIP_MEMORY_SCOPE_AGENT);
            }
            ((unsigned*)&hbuf4[par][0])[ldsw] = (unsigned)v;
        }
        __syncthreads();

        // dots: 8 broadcast h uint4 (slice s) x 16 reg W -> 2 column sums
        const uint4* hv = &hbuf4[par][s * 9];
        float a0 = 0.f, a1 = 0.f;
#pragma unroll
        for (int j = 0; j < 8; ++j) {
            uint4 hj = hv[j];
            a0 = dot4(W[j], hj, a0);
            a1 = dot4(W[8 + j], hj, a1);
        }

        // 8-lane reduce on the VALU (xor1, xor2, half-mirror)
        a0 = dpp_add<0xB1>(a0); a0 = dpp_add<0x4E>(a0); a0 = dpp_add<0x141>(a0);
        a1 = dpp_add<0xB1>(a1); a1 = dpp_add<0x4E>(a1); a1 = dpp_add<0x141>(a1);

        if (s < 2) {
            float tot = (s == 0) ? a0 : a1;
            float hn = fast_tanh(tot + xv);
            float hi = dpp_get<0xB1>(hn);        // lane0 pulls lane1's value
            if (s == 0) {
                unsigned pv = pack2h(hn, hi);
                ((unsigned*)&hbuf4[par ^ 1][0])[wordC] = pv;   // own next-state
                hp32[(size_t)step * 256] = pv;                 // hs output
                unsigned long long pubv =
                    ((unsigned long long)(unsigned)(step + 1) << 32) | pv;
                __hip_atomic_store(pub[(step + 1) & 1], pubv,
                                   __ATOMIC_RELAXED, __HIP_MEMORY_SCOPE_AGENT);
            }
        }
        // no end barrier: next step's __syncthreads orders hbuf[par^1] writes
    }
}

extern "C" void kernel_launch(void* const* d_in, const int* in_sizes, int n_in,
                              void* d_out, int out_size, void* d_ws, size_t ws_size,
                              hipStream_t stream) {
    const float* x    = (const float*)d_in[0];   // [64,1024,256]
    const float* W_xh = (const float*)d_in[1];   // [256,512]
    const float* W_hh = (const float*)d_in[2];   // [512,512]
    const float* b_h  = (const float*)d_in[3];   // [512]
    const float* W_hy = (const float*)d_in[4];   // [512,256]
    const float* b_y  = (const float*)d_in[5];   // [256]
    float* out = (float*)d_out;                  // [64,1024,256]

    char* ws = (char*)d_ws;
    unsigned* wblob = (unsigned*)ws;                              // 512 KiB
    unsigned long long* exch = (unsigned long long*)(ws + (512 << 10)); // 256 KiB
    __half* xh = (__half*)(ws + (1 << 20));                       // 64 MiB
    __half* hs = (__half*)(ws + (1 << 20) + (size_t)BT * HID * 2);// 64 MiB

    // 1) pack W_hh -> per-thread f16 blobs (4-CU-split geometry) + zero exch
    pack_w4_kernel<<<dim3(512), dim3(256), 0, stream>>>(W_hh, wblob, exch);

    // 2) xh = x @ W_xh + b_h   (f32 math -> f16 C; feeds the recurrence)
    gemm_bias_kernel<float, __half>
        <<<dim3(BT / 64, HID / 64), dim3(256), 0, stream>>>(x, W_xh, b_h, xh, BT, HID, NIN);

    // 3) scan: 256 WGs = 64 rows x 4 column-quarters, lock-free u64 exchange
    rnn_scan4<<<dim3(4 * NBATCH), dim3(512), 0, stream>>>(
        xh, (const uint4*)wblob, hs, exch);

    // 4) out = hs @ W_hy + b_y   (packed f16 dot2; error does not recurse)
    gemm_bias_f16_kernel<__half, float>
        <<<dim3(BT / 64, NOUT / 64), dim3(256), 0, stream>>>(hs, W_hy, b_y, out, BT, NOUT, HID);
}